// Round 1
// baseline (538.282 us; speedup 1.0000x reference)
//
#include <hip/hip_runtime.h>
#include <math.h>

#define N_    16
#define CIN_  16
#define T_    512
#define V_    200
#define K_    3
#define COUT_ 64
#define H_    64
#define G_    256  // 4*H

// Workspace layout (float offsets):
//   a  : [0, 600)                 a[k][v] = sum_w A[k,v,w] / V
//   sa : [640, 643)               sa[k] = sum_v a[k][v]
//   xa : [1024, 1024+16*512*48)   xa[n][t][k*16+ci]
//   xW : [WS_XW, +512*16*256)     xW[t][n][g]  (gate pre-activations from input side)
#define WS_A  0
#define WS_SA 640
#define WS_XA 1024
#define WS_XW (WS_XA + N_ * T_ * K_ * CIN_)

// ---------------------------------------------------------------------------
// Kernel 1: copy A -> out[16:], compute a[k][v]
__global__ __launch_bounds__(256) void prep_kernel(const float* __restrict__ A,
                                                   float* __restrict__ out,
                                                   float* __restrict__ ws) {
    int tid = blockIdx.x * blockDim.x + threadIdx.x;
    if (tid < K_ * V_ * V_) out[16 + tid] = A[tid];
    if (tid < K_ * V_) {
        const float* row = A + (long)tid * V_;
        float s = 0.f;
        for (int w = 0; w < V_; ++w) s += row[w];
        ws[WS_A + tid] = s * (1.0f / V_);
    }
}

// Kernel 2: sa[k] = sum_v a[k][v]
__global__ void sa_kernel(float* __restrict__ ws) {
    int k = threadIdx.x;
    if (k < K_) {
        float s = 0.f;
        for (int v = 0; v < V_; ++v) s += ws[WS_A + k * V_ + v];
        ws[WS_SA + k] = s;
    }
}

// ---------------------------------------------------------------------------
// Kernel 3: xa[n][t][k*16+ci] = sum_v x[n][ci][t][v] * a[k][v]
// One wave per (n,ci,t) row; lanes stride over v (coalesced).
__global__ __launch_bounds__(256) void xa_kernel(const float* __restrict__ x,
                                                 float* __restrict__ ws) {
    __shared__ float aS[K_ * V_];
    int tid = threadIdx.x;
    for (int i = tid; i < K_ * V_; i += 256) aS[i] = ws[WS_A + i];
    __syncthreads();

    int wave = tid >> 6, lane = tid & 63;
    int row = blockIdx.x * 4 + wave;          // row = (n*CIN + ci)*T + t
    const float* xr = x + (long)row * V_;

    float s0 = 0.f, s1 = 0.f, s2 = 0.f;
    for (int v = lane; v < V_; v += 64) {
        float xv = xr[v];
        s0 = fmaf(xv, aS[v], s0);
        s1 = fmaf(xv, aS[V_ + v], s1);
        s2 = fmaf(xv, aS[2 * V_ + v], s2);
    }
    #pragma unroll
    for (int m = 1; m < 64; m <<= 1) {
        s0 += __shfl_xor(s0, m);
        s1 += __shfl_xor(s1, m);
        s2 += __shfl_xor(s2, m);
    }
    if (lane == 0) {
        int t  = row % T_;
        int nc = row / T_;
        int ci = nc % CIN_;
        int n  = nc / CIN_;
        long base = (long)(n * T_ + t) * (K_ * CIN_);
        ws[WS_XA + base + 0 * CIN_ + ci] = s0;
        ws[WS_XA + base + 1 * CIN_ + ci] = s1;
        ws[WS_XA + base + 2 * CIN_ + ci] = s2;
    }
}

// ---------------------------------------------------------------------------
// Kernel 4 (fused): seq[t][n][c] = sum_{k,ci} W_gcn[k*64+c][ci]*xa[n][t][k*16+ci]
//                                + sum_k b_gcn[k*64+c]*sa[k]
//                  xW[t][n][g]  = b_ih[g]+b_hh[g] + sum_c seq[c]*W_ih[g][c]
// One block per (n,t) pair.
__global__ __launch_bounds__(256) void gates_pre_kernel(
    const float* __restrict__ W_gcn, const float* __restrict__ b_gcn,
    const float* __restrict__ W_ih, const float* __restrict__ b_ih,
    const float* __restrict__ b_hh, float* __restrict__ ws) {
    int nt = blockIdx.x;
    int t = nt % T_, n = nt / T_;
    __shared__ float xaS[K_ * CIN_];
    __shared__ float seqS[COUT_];
    int tid = threadIdx.x;
    if (tid < K_ * CIN_)
        xaS[tid] = ws[WS_XA + (long)(n * T_ + t) * (K_ * CIN_) + tid];
    __syncthreads();
    if (tid < COUT_) {
        float s = 0.f;
        #pragma unroll
        for (int k = 0; k < K_; ++k) {
            s = fmaf(b_gcn[k * COUT_ + tid], ws[WS_SA + k], s);
            const float* wrow = W_gcn + (long)(k * COUT_ + tid) * CIN_;
            #pragma unroll
            for (int ci = 0; ci < CIN_; ++ci)
                s = fmaf(wrow[ci], xaS[k * CIN_ + ci], s);
        }
        seqS[tid] = s;
    }
    __syncthreads();
    float g = b_ih[tid] + b_hh[tid];
    const float* wrow = W_ih + (long)tid * H_;
    #pragma unroll 8
    for (int c = 0; c < H_; ++c) g = fmaf(wrow[c], seqS[c], g);
    ws[WS_XW + (long)(t * N_ + n) * G_ + tid] = g;
}

// ---------------------------------------------------------------------------
// Kernel 5: sequential LSTM scan. One block per batch element n; 256 threads,
// thread g owns gate g (W_hh row in registers). h broadcast via LDS.
__global__ __launch_bounds__(256) void lstm_kernel(
    const float* __restrict__ W_hh, const float* __restrict__ W_fc,
    const float* __restrict__ b_fc, const float* __restrict__ ws,
    float* __restrict__ out) {
    int n = blockIdx.x;
    int g = threadIdx.x;

    float whh[H_];
    #pragma unroll
    for (int c = 0; c < H_; ++c) whh[c] = W_hh[(long)g * H_ + c];

    __shared__ float hS[H_];
    __shared__ float gbuf[G_];
    if (g < H_) hS[g] = 0.f;
    float ccell = 0.f;  // used by g < 64
    __syncthreads();

    const float* xw = ws + WS_XW + (long)n * G_ + g;
    for (int t = 0; t < T_; ++t) {
        float gate = xw[(long)t * N_ * G_];
        const float4* h4 = (const float4*)hS;
        #pragma unroll
        for (int c4 = 0; c4 < H_ / 4; ++c4) {
            float4 hv = h4[c4];
            gate = fmaf(whh[4 * c4 + 0], hv.x, gate);
            gate = fmaf(whh[4 * c4 + 1], hv.y, gate);
            gate = fmaf(whh[4 * c4 + 2], hv.z, gate);
            gate = fmaf(whh[4 * c4 + 3], hv.w, gate);
        }
        gbuf[g] = gate;
        __syncthreads();
        if (g < H_) {
            float iv = 1.f / (1.f + __expf(-gbuf[g]));
            float fv = 1.f / (1.f + __expf(-gbuf[H_ + g]));
            float gv = tanhf(gbuf[2 * H_ + g]);
            float ov = 1.f / (1.f + __expf(-gbuf[3 * H_ + g]));
            ccell = fv * ccell + iv * gv;
            hS[g] = ov * tanhf(ccell);
        }
        __syncthreads();
    }

    if (g < H_) {
        float p = hS[g] * W_fc[g];
        #pragma unroll
        for (int m = 1; m < 64; m <<= 1) p += __shfl_xor(p, m);
        if (g == 0) out[n] = p + b_fc[0];
    }
}

// ---------------------------------------------------------------------------
extern "C" void kernel_launch(void* const* d_in, const int* in_sizes, int n_in,
                              void* d_out, int out_size, void* d_ws, size_t ws_size,
                              hipStream_t stream) {
    const float* x     = (const float*)d_in[0];
    const float* A     = (const float*)d_in[1];
    const float* W_gcn = (const float*)d_in[2];
    const float* b_gcn = (const float*)d_in[3];
    const float* W_ih  = (const float*)d_in[4];
    const float* W_hh  = (const float*)d_in[5];
    const float* b_ih  = (const float*)d_in[6];
    const float* b_hh  = (const float*)d_in[7];
    const float* W_fc  = (const float*)d_in[8];
    const float* b_fc  = (const float*)d_in[9];
    float* out = (float*)d_out;
    float* ws  = (float*)d_ws;

    // 1) copy A to out, compute a[k][v]
    int copy_elems = K_ * V_ * V_;
    prep_kernel<<<(copy_elems + 255) / 256, 256, 0, stream>>>(A, out, ws);
    // 2) sa[k]
    sa_kernel<<<1, 64, 0, stream>>>(ws);
    // 3) xa
    int rows = N_ * CIN_ * T_;             // 131072, one wave each
    xa_kernel<<<rows / 4, 256, 0, stream>>>(x, ws);
    // 4) seq + input-side gate pre-activations
    gates_pre_kernel<<<N_ * T_, 256, 0, stream>>>(W_gcn, b_gcn, W_ih, b_ih, b_hh, ws);
    // 5) sequential LSTM scan + final FC
    lstm_kernel<<<N_, 256, 0, stream>>>(W_hh, W_fc, b_fc, ws, out);
}

// Round 2
// 429.624 us; speedup vs baseline: 1.2529x; 1.2529x over previous
//
#include <hip/hip_runtime.h>
#include <math.h>

#define N_    16
#define CIN_  16
#define T_    512
#define V_    200
#define K_    3
#define COUT_ 64
#define H_    64
#define G_    256  // 4*H

// Workspace layout (float offsets):
//   a  : [0, 600)                 a[k][v] = sum_w A[k,v,w] / V
//   sa : [640, 643)               sa[k] = sum_v a[k][v]
//   xa : [1024, 1024+16*512*48)   xa[n][t][k*16+ci]
//   xW : [WS_XW, +512*16*256)     xW[t][n][g]  (gate pre-activations from input side)
#define WS_A  0
#define WS_SA 640
#define WS_XA 1024
#define WS_XW (WS_XA + N_ * T_ * K_ * CIN_)

__device__ __forceinline__ float readlane_f(float v, int lane) {
    return __int_as_float(__builtin_amdgcn_readlane(__float_as_int(v), lane));
}

// ---------------------------------------------------------------------------
// Kernel 1: copy A -> out[16:], compute a[k][v]
__global__ __launch_bounds__(256) void prep_kernel(const float* __restrict__ A,
                                                   float* __restrict__ out,
                                                   float* __restrict__ ws) {
    int tid = blockIdx.x * blockDim.x + threadIdx.x;
    if (tid < K_ * V_ * V_) out[16 + tid] = A[tid];
    if (tid < K_ * V_) {
        const float* row = A + (long)tid * V_;
        float s = 0.f;
        for (int w = 0; w < V_; ++w) s += row[w];
        ws[WS_A + tid] = s * (1.0f / V_);
    }
}

// Kernel 2: sa[k] = sum_v a[k][v]
__global__ void sa_kernel(float* __restrict__ ws) {
    int k = threadIdx.x;
    if (k < K_) {
        float s = 0.f;
        for (int v = 0; v < V_; ++v) s += ws[WS_A + k * V_ + v];
        ws[WS_SA + k] = s;
    }
}

// ---------------------------------------------------------------------------
// Kernel 3: xa[n][t][k*16+ci] = sum_v x[n][ci][t][v] * a[k][v]
// One wave per (n,ci,t) row; lanes stride over v (coalesced).
__global__ __launch_bounds__(256) void xa_kernel(const float* __restrict__ x,
                                                 float* __restrict__ ws) {
    __shared__ float aS[K_ * V_];
    int tid = threadIdx.x;
    for (int i = tid; i < K_ * V_; i += 256) aS[i] = ws[WS_A + i];
    __syncthreads();

    int wave = tid >> 6, lane = tid & 63;
    int row = blockIdx.x * 4 + wave;          // row = (n*CIN + ci)*T + t
    const float* xr = x + (long)row * V_;

    float s0 = 0.f, s1 = 0.f, s2 = 0.f;
    for (int v = lane; v < V_; v += 64) {
        float xv = xr[v];
        s0 = fmaf(xv, aS[v], s0);
        s1 = fmaf(xv, aS[V_ + v], s1);
        s2 = fmaf(xv, aS[2 * V_ + v], s2);
    }
    #pragma unroll
    for (int m = 1; m < 64; m <<= 1) {
        s0 += __shfl_xor(s0, m);
        s1 += __shfl_xor(s1, m);
        s2 += __shfl_xor(s2, m);
    }
    if (lane == 0) {
        int t  = row % T_;
        int nc = row / T_;
        int ci = nc % CIN_;
        int n  = nc / CIN_;
        long base = (long)(n * T_ + t) * (K_ * CIN_);
        ws[WS_XA + base + 0 * CIN_ + ci] = s0;
        ws[WS_XA + base + 1 * CIN_ + ci] = s1;
        ws[WS_XA + base + 2 * CIN_ + ci] = s2;
    }
}

// ---------------------------------------------------------------------------
// Kernel 4 (fused): seq[t][n][c] = sum_{k,ci} W_gcn[k*64+c][ci]*xa[n][t][k*16+ci]
//                                + sum_k b_gcn[k*64+c]*sa[k]
//                  xW[t][n][g]  = b_ih[g]+b_hh[g] + sum_c seq[c]*W_ih[g][c]
// One block per (n,t) pair.
__global__ __launch_bounds__(256) void gates_pre_kernel(
    const float* __restrict__ W_gcn, const float* __restrict__ b_gcn,
    const float* __restrict__ W_ih, const float* __restrict__ b_ih,
    const float* __restrict__ b_hh, float* __restrict__ ws) {
    int nt = blockIdx.x;
    int t = nt % T_, n = nt / T_;
    __shared__ float xaS[K_ * CIN_];
    __shared__ float seqS[COUT_];
    int tid = threadIdx.x;
    if (tid < K_ * CIN_)
        xaS[tid] = ws[WS_XA + (long)(n * T_ + t) * (K_ * CIN_) + tid];
    __syncthreads();
    if (tid < COUT_) {
        float s = 0.f;
        #pragma unroll
        for (int k = 0; k < K_; ++k) {
            s = fmaf(b_gcn[k * COUT_ + tid], ws[WS_SA + k], s);
            const float* wrow = W_gcn + (long)(k * COUT_ + tid) * CIN_;
            #pragma unroll
            for (int ci = 0; ci < CIN_; ++ci)
                s = fmaf(wrow[ci], xaS[k * CIN_ + ci], s);
        }
        seqS[tid] = s;
    }
    __syncthreads();
    float g = b_ih[tid] + b_hh[tid];
    const float* wrow = W_ih + (long)tid * H_;
    #pragma unroll 8
    for (int c = 0; c < H_; ++c) g = fmaf(wrow[c], seqS[c], g);
    ws[WS_XW + (long)(t * N_ + n) * G_ + tid] = g;
}

// ---------------------------------------------------------------------------
// Kernel 5: sequential LSTM scan. One block per batch element n; 4 waves,
// wave w computes gate type w (i,f,g,o) for all 64 h-indices. h and ccell are
// kept in registers, replicated identically in every wave; the h·W_hh dot uses
// v_readlane broadcasts (no LDS). Only the 4 gate values per h-index cross
// waves, via a double-buffered LDS exchange with ONE barrier per step.
__global__ __launch_bounds__(256) void lstm_kernel(
    const float* __restrict__ W_hh, const float* __restrict__ W_fc,
    const float* __restrict__ b_fc, const float* __restrict__ ws,
    float* __restrict__ out) {
    int n = blockIdx.x;
    int w = threadIdx.x >> 6;     // gate type (torch order: i,f,g,o)
    int lane = threadIdx.x & 63;  // h index

    // W_hh row for (gate w, h-index lane) in registers.
    float whh[H_];
    const float* wr = W_hh + (long)(w * H_ + lane) * H_;
    #pragma unroll
    for (int c = 0; c < H_; ++c) whh[c] = wr[c];

    __shared__ float gbuf[2][4][H_];  // double-buffered gate exchange

    float h = 0.f, ccell = 0.f;       // replicated per wave (identical)

    const float* xw = ws + WS_XW + (long)n * G_ + (w * H_ + lane);
    // depth-2 software prefetch of the input-side gate pre-activations
    float x0 = xw[0];
    float x1 = xw[(long)N_ * G_];

    for (int t = 0; t < T_; ++t) {
        float gate = x0;
        x0 = x1;
        if (t + 2 < T_) x1 = xw[(long)(t + 2) * N_ * G_];

        // gate += dot(W_hh row, h-vector) — h broadcast via readlane,
        // 4 accumulators to break the dependence chain.
        float a0 = 0.f, a1 = 0.f, a2 = 0.f, a3 = 0.f;
        #pragma unroll
        for (int c4 = 0; c4 < H_ / 4; ++c4) {
            a0 = fmaf(whh[4 * c4 + 0], readlane_f(h, 4 * c4 + 0), a0);
            a1 = fmaf(whh[4 * c4 + 1], readlane_f(h, 4 * c4 + 1), a1);
            a2 = fmaf(whh[4 * c4 + 2], readlane_f(h, 4 * c4 + 2), a2);
            a3 = fmaf(whh[4 * c4 + 3], readlane_f(h, 4 * c4 + 3), a3);
        }
        gate += (a0 + a1) + (a2 + a3);

        int p = t & 1;
        gbuf[p][w][lane] = gate;
        __syncthreads();
        float iv = gbuf[p][0][lane];
        float fv = gbuf[p][1][lane];
        float gv = gbuf[p][2][lane];
        float ov = gbuf[p][3][lane];
        iv = 1.f / (1.f + __expf(-iv));
        fv = 1.f / (1.f + __expf(-fv));
        gv = tanhf(gv);
        ov = 1.f / (1.f + __expf(-ov));
        ccell = fv * ccell + iv * gv;
        h = ov * tanhf(ccell);
        // no second barrier: buffer p is not rewritten until step t+2, which
        // every wave can only reach after all waves passed barrier t+1.
    }

    // out[n] = dot(h, W_fc) + b_fc — wave 0 only (h identical in all waves)
    if (w == 0) {
        float p = h * W_fc[lane];
        #pragma unroll
        for (int m = 1; m < 64; m <<= 1) p += __shfl_xor(p, m);
        if (lane == 0) out[n] = p + b_fc[0];
    }
}

// ---------------------------------------------------------------------------
extern "C" void kernel_launch(void* const* d_in, const int* in_sizes, int n_in,
                              void* d_out, int out_size, void* d_ws, size_t ws_size,
                              hipStream_t stream) {
    const float* x     = (const float*)d_in[0];
    const float* A     = (const float*)d_in[1];
    const float* W_gcn = (const float*)d_in[2];
    const float* b_gcn = (const float*)d_in[3];
    const float* W_ih  = (const float*)d_in[4];
    const float* W_hh  = (const float*)d_in[5];
    const float* b_ih  = (const float*)d_in[6];
    const float* b_hh  = (const float*)d_in[7];
    const float* W_fc  = (const float*)d_in[8];
    const float* b_fc  = (const float*)d_in[9];
    float* out = (float*)d_out;
    float* ws  = (float*)d_ws;

    // 1) copy A to out, compute a[k][v]
    int copy_elems = K_ * V_ * V_;
    prep_kernel<<<(copy_elems + 255) / 256, 256, 0, stream>>>(A, out, ws);
    // 2) sa[k]
    sa_kernel<<<1, 64, 0, stream>>>(ws);
    // 3) xa
    int rows = N_ * CIN_ * T_;             // 131072 rows, one wave each
    xa_kernel<<<rows / 4, 256, 0, stream>>>(x, ws);
    // 4) seq + input-side gate pre-activations
    gates_pre_kernel<<<N_ * T_, 256, 0, stream>>>(W_gcn, b_gcn, W_ih, b_ih, b_hh, ws);
    // 5) sequential LSTM scan + final FC
    lstm_kernel<<<N_, 256, 0, stream>>>(W_hh, W_fc, b_fc, ws, out);
}

// Round 3
// 401.952 us; speedup vs baseline: 1.3392x; 1.0688x over previous
//
#include <hip/hip_runtime.h>
#include <math.h>

#define N_    16
#define CIN_  16
#define T_    512
#define V_    200
#define K_    3
#define COUT_ 64
#define H_    64
#define G_    256  // 4*H

// Workspace layout (float offsets):
//   a  : [0, 600)                 a[k][v] = sum_w A[k,v,w] / V
//   sa : [640, 643)               sa[k] = sum_v a[k][v]
//   xa : [1024, 1024+16*512*48)   xa[n][t][k*16+ci]
//   xW : [WS_XW, +512*16*256)     xW[t][n][g]  (gate pre-activations from input side)
#define WS_A  0
#define WS_SA 640
#define WS_XA 1024
#define WS_XW (WS_XA + N_ * T_ * K_ * CIN_)

// fast activations: v_exp_f32-based, ~1e-6 rel err, saturate correctly
__device__ __forceinline__ float fast_sig(float x) {
    return __builtin_amdgcn_rcpf(1.f + __expf(-x));
}
__device__ __forceinline__ float fast_tanh(float x) {
    // 1 - 2/(1+e^{2x}); x->+inf: rcp(inf)=0 -> 1; x->-inf: 1-2*rcp(1) = -1
    return fmaf(-2.f, __builtin_amdgcn_rcpf(1.f + __expf(2.f * x)), 1.f);
}

// ---------------------------------------------------------------------------
// Kernel 1: copy A -> out[16:], compute a[k][v]
__global__ __launch_bounds__(256) void prep_kernel(const float* __restrict__ A,
                                                   float* __restrict__ out,
                                                   float* __restrict__ ws) {
    int tid = blockIdx.x * blockDim.x + threadIdx.x;
    if (tid < K_ * V_ * V_) out[16 + tid] = A[tid];
    if (tid < K_ * V_) {
        const float* row = A + (long)tid * V_;
        float s = 0.f;
        for (int w = 0; w < V_; ++w) s += row[w];
        ws[WS_A + tid] = s * (1.0f / V_);
    }
}

// Kernel 2: sa[k] = sum_v a[k][v]
__global__ void sa_kernel(float* __restrict__ ws) {
    int k = threadIdx.x;
    if (k < K_) {
        float s = 0.f;
        for (int v = 0; v < V_; ++v) s += ws[WS_A + k * V_ + v];
        ws[WS_SA + k] = s;
    }
}

// ---------------------------------------------------------------------------
// Kernel 3: xa[n][t][k*16+ci] = sum_v x[n][ci][t][v] * a[k][v]
// One wave per (n,ci,t) row; lanes stride over v (coalesced).
__global__ __launch_bounds__(256) void xa_kernel(const float* __restrict__ x,
                                                 float* __restrict__ ws) {
    __shared__ float aS[K_ * V_];
    int tid = threadIdx.x;
    for (int i = tid; i < K_ * V_; i += 256) aS[i] = ws[WS_A + i];
    __syncthreads();

    int wave = tid >> 6, lane = tid & 63;
    int row = blockIdx.x * 4 + wave;          // row = (n*CIN + ci)*T + t
    const float* xr = x + (long)row * V_;

    float s0 = 0.f, s1 = 0.f, s2 = 0.f;
    for (int v = lane; v < V_; v += 64) {
        float xv = xr[v];
        s0 = fmaf(xv, aS[v], s0);
        s1 = fmaf(xv, aS[V_ + v], s1);
        s2 = fmaf(xv, aS[2 * V_ + v], s2);
    }
    #pragma unroll
    for (int m = 1; m < 64; m <<= 1) {
        s0 += __shfl_xor(s0, m);
        s1 += __shfl_xor(s1, m);
        s2 += __shfl_xor(s2, m);
    }
    if (lane == 0) {
        int t  = row % T_;
        int nc = row / T_;
        int ci = nc % CIN_;
        int n  = nc / CIN_;
        long base = (long)(n * T_ + t) * (K_ * CIN_);
        ws[WS_XA + base + 0 * CIN_ + ci] = s0;
        ws[WS_XA + base + 1 * CIN_ + ci] = s1;
        ws[WS_XA + base + 2 * CIN_ + ci] = s2;
    }
}

// ---------------------------------------------------------------------------
// Kernel 4 (fused): seq[t][n][c] = sum_{k,ci} W_gcn[k*64+c][ci]*xa[n][t][k*16+ci]
//                                + sum_k b_gcn[k*64+c]*sa[k]
//                  xW[t][n][g]  = b_ih[g]+b_hh[g] + sum_c seq[c]*W_ih[g][c]
// One block per (n,t) pair.
__global__ __launch_bounds__(256) void gates_pre_kernel(
    const float* __restrict__ W_gcn, const float* __restrict__ b_gcn,
    const float* __restrict__ W_ih, const float* __restrict__ b_ih,
    const float* __restrict__ b_hh, float* __restrict__ ws) {
    int nt = blockIdx.x;
    int t = nt % T_, n = nt / T_;
    __shared__ float xaS[K_ * CIN_];
    __shared__ float seqS[COUT_];
    int tid = threadIdx.x;
    if (tid < K_ * CIN_)
        xaS[tid] = ws[WS_XA + (long)(n * T_ + t) * (K_ * CIN_) + tid];
    __syncthreads();
    if (tid < COUT_) {
        float s = 0.f;
        #pragma unroll
        for (int k = 0; k < K_; ++k) {
            s = fmaf(b_gcn[k * COUT_ + tid], ws[WS_SA + k], s);
            const float* wrow = W_gcn + (long)(k * COUT_ + tid) * CIN_;
            #pragma unroll
            for (int ci = 0; ci < CIN_; ++ci)
                s = fmaf(wrow[ci], xaS[k * CIN_ + ci], s);
        }
        seqS[tid] = s;
    }
    __syncthreads();
    float g = b_ih[tid] + b_hh[tid];
    const float* wrow = W_ih + (long)tid * H_;
    #pragma unroll 8
    for (int c = 0; c < H_; ++c) g = fmaf(wrow[c], seqS[c], g);
    ws[WS_XW + (long)(t * N_ + n) * G_ + tid] = g;
}

// ---------------------------------------------------------------------------
// Kernel 5: sequential LSTM scan. One block per batch element; 4 waves,
// wave w = gate type (i,f,g,o), lane = gate index. W_hh row pinned in VGPRs
// (__launch_bounds__(256,1) so the allocator has a full budget). h broadcast
// from LDS via uniform-address ds_read_b128 (conflict-free), interleaved with
// the 64 FMAs. Wave 0 alone computes activations + state update.
__global__ __launch_bounds__(256, 1) void lstm_kernel(
    const float* __restrict__ W_hh, const float* __restrict__ W_fc,
    const float* __restrict__ b_fc, const float* __restrict__ ws,
    float* __restrict__ out) {
    int n = blockIdx.x;
    int w = threadIdx.x >> 6;     // gate type (torch order: i,f,g,o)
    int lane = threadIdx.x & 63;  // gate index / h index

    // W_hh row for (gate w, index lane), register-resident.
    float whh[H_];
    const float* wr = W_hh + (long)(w * H_ + lane) * H_;
    #pragma unroll
    for (int c = 0; c < H_; ++c) whh[c] = wr[c];

    __shared__ __align__(16) float hS[H_];
    __shared__ float gbuf[4][H_];

    if (threadIdx.x < H_) hS[threadIdx.x] = 0.f;
    float ccell = 0.f, hlast = 0.f;   // live only in wave 0
    __syncthreads();

    const float* xw = ws + WS_XW + (long)n * G_ + (w * H_ + lane);
    // depth-2 prefetch of the input-side gate pre-activations
    float x0 = xw[0];
    float x1 = xw[(long)N_ * G_];

    for (int t = 0; t < T_; ++t) {
        float gate = x0;
        x0 = x1;
        if (t + 2 < T_) x1 = xw[(long)(t + 2) * N_ * G_];

        // gate += dot(whh, h) — h streamed from LDS (uniform-address b128
        // broadcast), 4 accumulators for ILP.
        float a0 = 0.f, a1 = 0.f, a2 = 0.f, a3 = 0.f;
        const float4* h4 = (const float4*)hS;
        #pragma unroll
        for (int c4 = 0; c4 < H_ / 4; ++c4) {
            float4 hv = h4[c4];
            a0 = fmaf(whh[4 * c4 + 0], hv.x, a0);
            a1 = fmaf(whh[4 * c4 + 1], hv.y, a1);
            a2 = fmaf(whh[4 * c4 + 2], hv.z, a2);
            a3 = fmaf(whh[4 * c4 + 3], hv.w, a3);
        }
        gate += (a0 + a1) + (a2 + a3);

        gbuf[w][lane] = gate;
        __syncthreads();               // B1: gates visible
        if (w == 0) {
            float iv = fast_sig(gate);           // own gate == i
            float fv = fast_sig(gbuf[1][lane]);
            float gv = fast_tanh(gbuf[2][lane]);
            float ov = fast_sig(gbuf[3][lane]);
            ccell = fmaf(fv, ccell, iv * gv);
            hlast = ov * fast_tanh(ccell);
            hS[lane] = hlast;
        }
        __syncthreads();               // B2: new h visible
    }

    // out[n] = dot(h, W_fc) + b_fc  (wave 0 holds hlast)
    if (w == 0) {
        float p = hlast * W_fc[lane];
        #pragma unroll
        for (int m = 1; m < 64; m <<= 1) p += __shfl_xor(p, m);
        if (lane == 0) out[n] = p + b_fc[0];
    }
}

// ---------------------------------------------------------------------------
extern "C" void kernel_launch(void* const* d_in, const int* in_sizes, int n_in,
                              void* d_out, int out_size, void* d_ws, size_t ws_size,
                              hipStream_t stream) {
    const float* x     = (const float*)d_in[0];
    const float* A     = (const float*)d_in[1];
    const float* W_gcn = (const float*)d_in[2];
    const float* b_gcn = (const float*)d_in[3];
    const float* W_ih  = (const float*)d_in[4];
    const float* W_hh  = (const float*)d_in[5];
    const float* b_ih  = (const float*)d_in[6];
    const float* b_hh  = (const float*)d_in[7];
    const float* W_fc  = (const float*)d_in[8];
    const float* b_fc  = (const float*)d_in[9];
    float* out = (float*)d_out;
    float* ws  = (float*)d_ws;

    // 1) copy A to out, compute a[k][v]
    int copy_elems = K_ * V_ * V_;
    prep_kernel<<<(copy_elems + 255) / 256, 256, 0, stream>>>(A, out, ws);
    // 2) sa[k]
    sa_kernel<<<1, 64, 0, stream>>>(ws);
    // 3) xa
    int rows = N_ * CIN_ * T_;             // 131072 rows, one wave each
    xa_kernel<<<rows / 4, 256, 0, stream>>>(x, ws);
    // 4) seq + input-side gate pre-activations
    gates_pre_kernel<<<N_ * T_, 256, 0, stream>>>(W_gcn, b_gcn, W_ih, b_ih, b_hh, ws);
    // 5) sequential LSTM scan + final FC
    lstm_kernel<<<N_, 256, 0, stream>>>(W_hh, W_fc, b_fc, ws, out);
}